// Round 5
// baseline (686.600 us; speedup 1.0000x reference)
//
#include <hip/hip_runtime.h>
#include <hip/hip_bf16.h>

// Problem constants
#define T_TOK 8192
#define E_EXP 8
#define D_HID 1024
#define F_FFN 4096
#define C_CAP 2048   // T * 2.0 / E

typedef __attribute__((ext_vector_type(8))) short bf16x8;  // 8 bf16 (4 VGPRs)
typedef __attribute__((ext_vector_type(4))) float f32x4;   // 4 fp32 acc

// Async global->LDS, 16 B per lane. LDS dest is wave-uniform base + lane*16;
// source address may be per-lane (gather OK).
__device__ __forceinline__ void load_lds16(const void* g, void* l) {
    __builtin_amdgcn_global_load_lds(
        (const __attribute__((address_space(1))) unsigned int*)g,
        (__attribute__((address_space(3))) unsigned int*)l, 16, 0, 0);
}

// gelu(v) = v * sigmoid(1.595769 v + 0.0713548 v^3); __expf -> v_exp_f32.
__device__ __forceinline__ float gelu_fast(float v) {
    float z = v * (1.5957691216057308f + 0.07135481627f * v * v);
    return v / (1.0f + __expf(-z));
}

// ---------------------------------------------------------------------------
// Kernel 1: router gating (fp32 exact) + fused x->bf16 convert + aux const.
// aux = E*(C/T)*sum_e mean_t gates = E*(C/T) exactly (softmax rows sum to 1).
// ---------------------------------------------------------------------------
__global__ __launch_bounds__(256) void gating_kernel(
    const float* __restrict__ x, const float* __restrict__ Wg,
    float* __restrict__ gatesT, __hip_bfloat16* __restrict__ xbf,
    float* __restrict__ aux_out)
{
    const int token = blockIdx.x * 4 + (threadIdx.x >> 6);
    const int lane  = threadIdx.x & 63;
    if (token == 0 && lane == 0)
        aux_out[0] = (float)E_EXP * (float)C_CAP / (float)T_TOK;   // == 2.0f
    const float* xr = x + (size_t)token * D_HID;

    float acc[E_EXP];
#pragma unroll
    for (int e = 0; e < E_EXP; ++e) acc[e] = 0.0f;

#pragma unroll
    for (int it = 0; it < 4; ++it) {
        const int c4 = it * 64 + lane;               // float4 index in row
        float4 v = ((const float4*)xr)[c4];
        float vv[4] = {v.x, v.y, v.z, v.w};
        union { __hip_bfloat16 h[4]; short4 s; } u;
#pragma unroll
        for (int j = 0; j < 4; ++j) u.h[j] = __float2bfloat16(vv[j]);
        ((short4*)(xbf + (size_t)token * D_HID))[c4] = u.s;
        const float* wr0 = Wg + (size_t)c4 * 4 * E_EXP;
#pragma unroll
        for (int j = 0; j < 4; ++j)
#pragma unroll
            for (int e = 0; e < E_EXP; ++e) acc[e] += vv[j] * wr0[j * E_EXP + e];
    }
#pragma unroll
    for (int e = 0; e < E_EXP; ++e) {
        for (int off = 32; off; off >>= 1) acc[e] += __shfl_down(acc[e], off);
    }
    if (lane == 0) {
        float m = acc[0];
#pragma unroll
        for (int e = 1; e < E_EXP; ++e) m = fmaxf(m, acc[e]);
        float ex[E_EXP];
        float s = 0.0f;
#pragma unroll
        for (int e = 0; e < E_EXP; ++e) { ex[e] = expf(acc[e] - m); s += ex[e]; }
        float inv = 1.0f / s;
#pragma unroll
        for (int e = 0; e < E_EXP; ++e) gatesT[(size_t)e * T_TOK + token] = ex[e] * inv;
    }
}

// ---------------------------------------------------------------------------
// Kernel 3: exact per-expert top-C via register radix-select, NO sort.
// Selected SET is bit-identical to jax top_k (keys embed the tie-break);
// output order within an expert is irrelevant downstream.
// ---------------------------------------------------------------------------
__global__ __launch_bounds__(1024) void topk_kernel(
    const float* __restrict__ gatesT, int* __restrict__ topidx,
    float* __restrict__ topval, int* __restrict__ cnt, int* __restrict__ inv)
{
    __shared__ unsigned int hist[256];
    __shared__ unsigned int bc_v, bc_r;
    __shared__ unsigned int selcnt;

    const int e    = blockIdx.x;
    const int tid  = threadIdx.x;
    const int lane = tid & 63;
    const float* row = gatesT + (size_t)e * T_TOK;

    unsigned long long kreg[8];
#pragma unroll
    for (int p = 0; p < 8; ++p) {
        int i = tid + p * 1024;
        unsigned int b = __float_as_uint(row[i]);
        b = (b & 0x80000000u) ? ~b : (b | 0x80000000u);
        kreg[p] = ((unsigned long long)b << 32) | (unsigned int)(T_TOK - 1 - i);
    }
    if (tid == 0) selcnt = 0;

    unsigned long long prefix = 0ull, mask = 0ull;
    unsigned int rank = C_CAP;
    for (int byte = 7; byte >= 0; --byte) {
        if (tid < 256) hist[tid] = 0;
        __syncthreads();
        const int sh = byte * 8;
#pragma unroll
        for (int p = 0; p < 8; ++p) {
            unsigned long long k = kreg[p];
            if ((k & mask) == prefix)
                atomicAdd(&hist[(unsigned int)((k >> sh) & 255ull)], 1u);
        }
        __syncthreads();
        if (tid < 64) {
            unsigned int v0 = hist[tid * 4], v1 = hist[tid * 4 + 1];
            unsigned int v2 = hist[tid * 4 + 2], v3 = hist[tid * 4 + 3];
            unsigned int s3 = v3, s2 = v2 + s3, s1 = v1 + s2, s0 = v0 + s1;
            unsigned int t = s0;
#pragma unroll
            for (int off = 1; off < 64; off <<= 1) {
                unsigned int u = __shfl_down(t, off);
                if (lane + off < 64) t += u;
            }
            const unsigned int suf = t - s0;
            unsigned int ge[4] = {s0 + suf, s1 + suf, s2 + suf, s3 + suf};
            unsigned int gt[4] = {s1 + suf, s2 + suf, s3 + suf, suf};
#pragma unroll
            for (int j = 0; j < 4; ++j)
                if (ge[j] >= rank && gt[j] < rank) {
                    bc_v = (unsigned int)(tid * 4 + j); bc_r = rank - gt[j];
                }
        }
        __syncthreads();
        prefix |= ((unsigned long long)bc_v) << sh;
        mask   |= (0xFFull << sh);
        rank = bc_r;
        __syncthreads();
    }
    const unsigned long long thr = prefix;

#pragma unroll
    for (int p = 0; p < 8; ++p) {
        unsigned long long k = kreg[p];
        if (k >= thr) {
            int c = (int)atomicAdd(&selcnt, 1u);
            int idx = T_TOK - 1 - (int)(k & 0xFFFFFFFFull);
            unsigned int b = (unsigned int)(k >> 32);
            b = (b & 0x80000000u) ? (b & 0x7FFFFFFFu) : ~b;
            topidx[e * C_CAP + c] = idx;
            topval[e * C_CAP + c] = __uint_as_float(b);
            int slot = atomicAdd(&cnt[idx], 1);   // <=8 entries per token
            inv[idx * E_EXP + slot] = e * C_CAP + c;
        }
    }
}

// ---------------------------------------------------------------------------
// Kernel 5: both weight transposes in ONE launch.
// z<8:  W1 [D,F] -> W1t [F,D], expert z.  z>=8: W2 [F,D] -> W2t [D,F].
// ---------------------------------------------------------------------------
__global__ __launch_bounds__(256) void transpose_bf16_kernel(
    const float* __restrict__ W1, __hip_bfloat16* __restrict__ W1t,
    const float* __restrict__ W2, __hip_bfloat16* __restrict__ W2t)
{
    __shared__ float tile[64][65];
    const int z = blockIdx.z;
    const float* in;
    __hip_bfloat16* out;
    int R, Cn, c0, r0;
    if (z < 8) {
        R = D_HID; Cn = F_FFN;
        in = W1 + (size_t)z * R * Cn; out = W1t + (size_t)z * R * Cn;
        c0 = blockIdx.x * 64; r0 = blockIdx.y * 64;
    } else {
        R = F_FFN; Cn = D_HID;
        in = W2 + (size_t)(z - 8) * R * Cn; out = W2t + (size_t)(z - 8) * R * Cn;
        c0 = blockIdx.y * 64; r0 = blockIdx.x * 64;
    }
    const int tid = threadIdx.x;

    const int lr = tid >> 4, lc4 = (tid & 15) * 4;
#pragma unroll
    for (int it = 0; it < 4; ++it) {
        int r = lr + it * 16;
        float4 v = *(const float4*)(in + (size_t)(r0 + r) * Cn + c0 + lc4);
        tile[r][lc4 + 0] = v.x; tile[r][lc4 + 1] = v.y;
        tile[r][lc4 + 2] = v.z; tile[r][lc4 + 3] = v.w;
    }
    __syncthreads();

    const int ocb = tid >> 3, j0 = (tid & 7) * 8;
#pragma unroll
    for (int it = 0; it < 2; ++it) {
        int oc = ocb + it * 32;
        union { __hip_bfloat16 h[8]; uint4 v; } u;
#pragma unroll
        for (int j = 0; j < 8; ++j) u.h[j] = __float2bfloat16(tile[j0 + j][oc]);
        *(uint4*)(out + (size_t)(c0 + oc) * R + r0 + j0) = u.v;
    }
}

// ===========================================================================
// Shared pipeline primitives (verified rounds 1-3).
// ===========================================================================
#define BARS do { __builtin_amdgcn_s_barrier(); __builtin_amdgcn_sched_barrier(0); } while (0)
#define WLG  do { asm volatile("s_waitcnt lgkmcnt(0)" ::: "memory"); __builtin_amdgcn_sched_barrier(0); } while (0)
#define VMC4 asm volatile("s_waitcnt vmcnt(4)" ::: "memory")
#define VMC0 asm volatile("s_waitcnt vmcnt(0)" ::: "memory")

// ---------------------------------------------------------------------------
// Kernel 6: GEMM1 — NEW 128x128 / 2-blocks-per-CU variant (desync experiment).
// h[e] = gelu(gather(x)[C,D] @ W1t[e]^T + b1[e]).  M=2048,N=4096,K=1024/expert.
// 256 thr (4 waves, 2Mx2N, 64x64 per wave). LDS exactly 80 KiB:
//   A triple-buffer 3x16K (slot = t mod 3) | B double-buffer 2x16K @49152.
// Per K-tile: {read A+B01, stage B(t+1), lgkm0, 16 MFMA, read B23,
//   stage A(t+2), lgkm0, 16 MFMA, vmcnt(4), barrier} — ONE barrier/tile.
// vmcnt(4) retires exactly A(t+1)+B(t+1) (issue order verified); A staged
// 2 tiles ahead. Two co-resident blocks desynchronize read/MFMA regions.
// ---------------------------------------------------------------------------
#define S1A(s, slot) do { _Pragma("unroll") for (int j = 0; j < 4; ++j) \
    load_lds16(Abase + (size_t)(aog[j] + (s) * 128), smem + (slot) * 16384 + j * 4096 + w * 1024); } while (0)
#define S1B(s) do { _Pragma("unroll") for (int j = 0; j < 4; ++j) \
    load_lds16(Bbase + (size_t)(bog[j] + (s) * 128), smem + 49152 + ((s) & 1) * 16384 + j * 4096 + w * 1024); } while (0)

__global__ __launch_bounds__(256, 2) void gemm1_kernel(
    const __hip_bfloat16* __restrict__ xb,   // [T][D]
    const __hip_bfloat16* __restrict__ W1t,  // [E][F][D]
    const float* __restrict__ b1,            // [E][F]
    const int* __restrict__ topidx,          // [E][C]
    __hip_bfloat16* __restrict__ hbuf)       // [E][C][F]
{
    __shared__ __align__(16) char smem[81920];
    const int tid = threadIdx.x;
    const int w = tid >> 6, lane = tid & 63;
    const int wr = w >> 1, wc = w & 1;
    const int fr = lane & 15, qlane = lane >> 4;

    // XCD-bijective swizzle (4096 % 8 == 0), m-fastest within expert:
    // 64 concurrent blocks/XCD span 4 n-panels => 1 MB B-slice, L2-resident.
    const int bid = blockIdx.x;
    const int wg  = (bid & 7) * 512 + (bid >> 3);
    const int e   = wg >> 9;
    const int idx = wg & 511;
    const int m0  = (idx & 15) * 128;
    const int n0  = (idx >> 4) * 128;

    const char* Abase = (const char*)xb;
    const char* Bbase = (const char*)(W1t + (size_t)e * F_FFN * D_HID);

    // staging source byte offsets (inverse-swizzled column chunk)
    const int cc = (tid & 7) ^ ((tid >> 3) & 7);
    int aog[4], bog[4];
#pragma unroll
    for (int j = 0; j < 4; ++j) {
        int r   = j * 32 + (tid >> 3);
        int tok = topidx[e * C_CAP + m0 + r];
        aog[j] = (tok * D_HID + cc * 8) * 2;
        int n = n0 + j * 32 + (tid >> 3);
        bog[j] = (n * D_HID + cc * 8) * 2;
    }

    const int arow = (wr * 64 + fr) * 128;
    const int brow = (wc * 64 + fr) * 128;
    const int kc0  = ((qlane)     ^ (lane & 7)) * 16;
    const int kc1  = ((4 + qlane) ^ (lane & 7)) * 16;

    bf16x8 aF[4][2], bF[4][2];
    f32x4 acc[4][4];
#pragma unroll
    for (int mi = 0; mi < 4; ++mi)
#pragma unroll
        for (int ni = 0; ni < 4; ++ni) acc[mi][ni] = (f32x4){0.f, 0.f, 0.f, 0.f};

    // Prologue: A(0)->slot0, B(0), A(1)->slot1. vmcnt(4) retires A(0),B(0),
    // leaves A(1) in flight (steady-state entry condition for t=0).
    S1A(0, 0); S1B(0); S1A(1, 1);
    VMC4; BARS;

    for (int t = 0; t < 16; ++t) {              // NT = K/64 = 16
        const char* Ab = smem + (t % 3) * 16384;
        const char* Bb = smem + 49152 + ((t & 1) << 14);
        // phase 0: all A frags + B frags 0-1; stage B(t+1)
#pragma unroll
        for (int mi = 0; mi < 4; ++mi) {
            aF[mi][0] = *(const bf16x8*)(Ab + (arow + mi * 2048 + kc0));
            aF[mi][1] = *(const bf16x8*)(Ab + (arow + mi * 2048 + kc1));
        }
#pragma unroll
        for (int ni = 0; ni < 2; ++ni) {
            bF[ni][0] = *(const bf16x8*)(Bb + (brow + ni * 2048 + kc0));
            bF[ni][1] = *(const bf16x8*)(Bb + (brow + ni * 2048 + kc1));
        }
        if (t + 1 < 16) S1B(t + 1);
        WLG;
        __builtin_amdgcn_s_setprio(1);
#pragma unroll
        for (int mi = 0; mi < 4; ++mi)
#pragma unroll
            for (int ni = 0; ni < 2; ++ni) {
                acc[mi][ni] = __builtin_amdgcn_mfma_f32_16x16x32_bf16(
                    aF[mi][0], bF[ni][0], acc[mi][ni], 0, 0, 0);
                acc[mi][ni] = __builtin_amdgcn_mfma_f32_16x16x32_bf16(
                    aF[mi][1], bF[ni][1], acc[mi][ni], 0, 0, 0);
            }
        __builtin_amdgcn_s_setprio(0);
        // phase 1: B frags 2-3; stage A(t+2)
#pragma unroll
        for (int ni = 2; ni < 4; ++ni) {
            bF[ni][0] = *(const bf16x8*)(Bb + (brow + ni * 2048 + kc0));
            bF[ni][1] = *(const bf16x8*)(Bb + (brow + ni * 2048 + kc1));
        }
        if (t + 2 < 16) { const int sl = (t + 2) % 3; S1A(t + 2, sl); }
        WLG;
        __builtin_amdgcn_s_setprio(1);
#pragma unroll
        for (int mi = 0; mi < 4; ++mi)
#pragma unroll
            for (int ni = 2; ni < 4; ++ni) {
                acc[mi][ni] = __builtin_amdgcn_mfma_f32_16x16x32_bf16(
                    aF[mi][0], bF[ni][0], acc[mi][ni], 0, 0, 0);
                acc[mi][ni] = __builtin_amdgcn_mfma_f32_16x16x32_bf16(
                    aF[mi][1], bF[ni][1], acc[mi][ni], 0, 0, 0);
            }
        __builtin_amdgcn_s_setprio(0);
        if (t + 2 < 16) { VMC4; } else { VMC0; }
        BARS;
    }

    // Epilogue: bias + gelu -> bf16 via LDS transpose (128 rows x 256 B,
    // fits in A slots; fully drained). Row-XOR swizzled 2-B writes, then
    // b128 reads + 16-B coalesced global stores (256 B per 16-lane group).
    const int q4 = qlane * 4;
    float b1v[4];
#pragma unroll
    for (int ni = 0; ni < 4; ++ni)
        b1v[ni] = b1[e * F_FFN + n0 + wc * 64 + ni * 16 + fr];
#pragma unroll
    for (int mi = 0; mi < 4; ++mi)
#pragma unroll
        for (int r = 0; r < 4; ++r) {
            const int row = wr * 64 + mi * 16 + q4 + r;
            char* rb = smem + row * 256;
            const int sw = (row & 7) << 4;
#pragma unroll
            for (int ni = 0; ni < 4; ++ni) {
                const int col2 = (wc * 64 + ni * 16 + fr) * 2;
                *(__hip_bfloat16*)(rb + (col2 ^ sw)) =
                    __float2bfloat16(gelu_fast(acc[mi][ni][r] + b1v[ni]));
            }
        }
    __syncthreads();
#pragma unroll
    for (int it = 0; it < 8; ++it) {
        const int row = it * 16 + (tid >> 4);
        const int cb  = (tid & 15) * 16;
        uint4 v = *(const uint4*)(smem + row * 256 + (cb ^ ((row & 7) << 4)));
        char* gp = (char*)(hbuf + ((size_t)e * C_CAP + m0 + row) * F_FFN + n0) + cb;
        *(uint4*)gp = v;
    }
}

// ---------------------------------------------------------------------------
// Kernel 7: GEMM2 (control: round-2/3 proven 256x256 8-phase, 2-buffer).
// yo[e][c] = (h[e] @ W2t[e]^T + b2[e]) * gate. M=2048,N=1024,K=4096.
// ---------------------------------------------------------------------------
#define STG2_A(hh, s) do { int b_ = (((s) & 1) << 15) + ((hh) << 14) + (w << 10); \
    load_lds16(Abase + (size_t)(aog[hh][0] + (s) * 128), smem + b_); \
    load_lds16(Abase + (size_t)(aog[hh][1] + (s) * 128), smem + b_ + 8192); } while (0)
#define STG2_B(hh, s) do { int b_ = 65536 + (((s) & 1) << 15) + ((hh) << 14) + (w << 10); \
    load_lds16(Bbase + (size_t)(bog[hh][0] + (s) * 128), smem + b_); \
    load_lds16(Bbase + (size_t)(bog[hh][1] + (s) * 128), smem + b_ + 8192); } while (0)

#define READ_A(mh) do { _Pragma("unroll") for (int mi = 0; mi < 4; ++mi) { \
    aF[mi][0] = *(const bf16x8*)(Ab + (arow + (mh) * 8192 + mi * 2048 + kc0)); \
    aF[mi][1] = *(const bf16x8*)(Ab + (arow + (mh) * 8192 + mi * 2048 + kc1)); } } while (0)
#define READ_B(nh, dst) do { _Pragma("unroll") for (int ni = 0; ni < 2; ++ni) { \
    dst[ni][0] = *(const bf16x8*)(Bb + (brow + (nh) * 4096 + ni * 2048 + kc0)); \
    dst[ni][1] = *(const bf16x8*)(Bb + (brow + (nh) * 4096 + ni * 2048 + kc1)); } } while (0)

#define QUAD(mh, nh, BF) do { \
    __builtin_amdgcn_s_setprio(1); \
    _Pragma("unroll") for (int mi = 0; mi < 4; ++mi) \
    _Pragma("unroll") for (int ni = 0; ni < 2; ++ni) { \
        acc[(mh)*4+mi][(nh)*2+ni] = __builtin_amdgcn_mfma_f32_16x16x32_bf16( \
            aF[mi][0], BF[ni][0], acc[(mh)*4+mi][(nh)*2+ni], 0, 0, 0); \
        acc[(mh)*4+mi][(nh)*2+ni] = __builtin_amdgcn_mfma_f32_16x16x32_bf16( \
            aF[mi][1], BF[ni][1], acc[(mh)*4+mi][(nh)*2+ni], 0, 0, 0); } \
    __builtin_amdgcn_s_setprio(0); } while (0)

#define GEMM_PROLOGUE_G() do { \
    STG2_A(0, 0); STG2_A(1, 0); STG2_B(0, 0); STG2_B(1, 0); \
    STG2_B(0, 1); STG2_B(1, 1); \
    VMC4; BARS; } while (0)

#define GEMM_TILE_G(t, NT) do { \
    const char* Ab = smem + (((t) & 1) << 15); \
    const char* Bb = smem + 65536 + (((t) & 1) << 15); \
    READ_A(0); READ_B(0, bF0); \
    if ((t) + 1 < (NT)) STG2_A(0, (t) + 1); \
    BARS; WLG; QUAD(0, 0, bF0); BARS; \
    READ_B(1, bF1); \
    if ((t) + 1 < (NT)) STG2_A(1, (t) + 1); \
    BARS; WLG; QUAD(0, 1, bF1); BARS; \
    READ_A(1); \
    if ((t) + 2 < (NT)) STG2_B(0, (t) + 2); \
    BARS; WLG; QUAD(1, 1, bF1); BARS; \
    if ((t) + 2 < (NT)) STG2_B(1, (t) + 2); \
    BARS; WLG; QUAD(1, 0, bF0); \
    if ((t) + 2 < (NT)) { VMC4; } else { VMC0; } \
    BARS; } while (0)

__global__ __launch_bounds__(512, 2) void gemm2_kernel(
    const __hip_bfloat16* __restrict__ hbuf, // [E][C][F]
    const __hip_bfloat16* __restrict__ W2t,  // [E][D][F]
    const float* __restrict__ b2,            // [E][D]
    const float* __restrict__ topval,        // [E][C]
    float* __restrict__ yo)                  // [E][C][D]
{
    __shared__ __align__(16) char smem[131072];
    const int tid = threadIdx.x;
    const int w = tid >> 6, lane = tid & 63;
    const int wr = w >> 2, wc = w & 3;
    const int fr = lane & 15, qlane = lane >> 4;

    const int bid = blockIdx.x;
    const int wg  = (bid & 7) * 32 + (bid >> 3);   // 256 % 8 == 0
    const int n0  = (wg & 3) * 256;
    const int m0  = ((wg >> 2) & 7) * 256;
    const int e   = wg >> 5;                        // one expert per XCD

    const char* Abase = (const char*)(hbuf + (size_t)e * C_CAP * F_FFN);
    const char* Bbase = (const char*)(W2t + (size_t)e * D_HID * F_FFN);

    const int cc = (tid & 7) ^ ((tid >> 3) & 7);
    int aog[2][2], bog[2][2];
#pragma unroll
    for (int hh = 0; hh < 2; ++hh)
#pragma unroll
        for (int j = 0; j < 2; ++j) {
            int r = m0 + hh * 128 + j * 64 + (tid >> 3);
            aog[hh][j] = (r * F_FFN + cc * 8) * 2;
            int n = n0 + hh * 128 + j * 64 + (tid >> 3);
            bog[hh][j] = (n * F_FFN + cc * 8) * 2;
        }

    const int arow = (wr * 128 + fr) * 128;
    const int brow = (wc * 64 + fr) * 128;
    const int kc0  = ((qlane)     ^ (lane & 7)) * 16;
    const int kc1  = ((4 + qlane) ^ (lane & 7)) * 16;

    bf16x8 aF[4][2], bF0[2][2], bF1[2][2];
    f32x4 acc[8][4];
#pragma unroll
    for (int mi = 0; mi < 8; ++mi)
#pragma unroll
        for (int ni = 0; ni < 4; ++ni) acc[mi][ni] = (f32x4){0.f, 0.f, 0.f, 0.f};

    GEMM_PROLOGUE_G();
#pragma unroll 2
    for (int t = 0; t < 64; ++t) GEMM_TILE_G(t, 64);   // NT = 4096/64

    // Epilogue: bias + gate weight, fp32; 16-lane groups write 64 B runs.
    const int q4 = qlane * 4;
    float b2v[4];
#pragma unroll
    for (int ni = 0; ni < 4; ++ni)
        b2v[ni] = b2[e * D_HID + n0 + wc * 64 + ni * 16 + fr];
#pragma unroll
    for (int mi = 0; mi < 8; ++mi) {
#pragma unroll
        for (int r = 0; r < 4; ++r) {
            const int row = m0 + wr * 128 + mi * 16 + q4 + r;
            const float g = topval[e * C_CAP + row];
            float* orow = yo + ((size_t)e * C_CAP + row) * D_HID + n0 + wc * 64;
#pragma unroll
            for (int ni = 0; ni < 4; ++ni)
                orow[ni * 16 + fr] = (acc[mi][ni][r] + b2v[ni]) * g;
        }
    }
}

// ---------------------------------------------------------------------------
// Kernel 8: combine — out[t] = sum over inv[t] entries of yo rows.
// ---------------------------------------------------------------------------
__global__ __launch_bounds__(256) void combine_kernel(
    const float* __restrict__ yo, const int* __restrict__ cnt,
    const int* __restrict__ inv, float* __restrict__ out)
{
    const int t = blockIdx.x;
    const int n = cnt[t];
    const int c4 = threadIdx.x * 4;
    float4 a = {0.f, 0.f, 0.f, 0.f};
    for (int k = 0; k < n; ++k) {
        int ec = inv[t * E_EXP + k];
        float4 v = *(const float4*)(yo + (size_t)ec * D_HID + c4);
        a.x += v.x; a.y += v.y; a.z += v.z; a.w += v.w;
    }
    *(float4*)(out + (size_t)t * D_HID + c4) = a;
}

// ---------------------------------------------------------------------------
extern "C" void kernel_launch(void* const* d_in, const int* in_sizes, int n_in,
                              void* d_out, int out_size, void* d_ws, size_t ws_size,
                              hipStream_t stream) {
    const float* x  = (const float*)d_in[0];   // [T, D]
    const float* Wg = (const float*)d_in[1];   // [D, E]
    const float* W1 = (const float*)d_in[2];   // [E, D, F]
    const float* b1 = (const float*)d_in[3];   // [E, F]
    const float* W2 = (const float*)d_in[4];   // [E, F, D]
    const float* b2 = (const float*)d_in[5];   // [E, D]
    float* out = (float*)d_out;                // [T*D] out ++ [1] aux

    // Workspace layout
    char* p = (char*)d_ws;
    float* gatesT = (float*)p;            p += (size_t)E_EXP * T_TOK * 4;      // 256 KB
    int*   topidx = (int*)p;              p += (size_t)E_EXP * C_CAP * 4;      // 64 KB
    float* topval = (float*)p;            p += (size_t)E_EXP * C_CAP * 4;      // 64 KB
    int*   cnt    = (int*)p;              p += (size_t)T_TOK * 4;              // 32 KB
    int*   inv    = (int*)p;              p += (size_t)T_TOK * E_EXP * 4;      // 256 KB
    __hip_bfloat16* x_bf = (__hip_bfloat16*)p;  p += (size_t)T_TOK * D_HID * 2;         // 16.8 MB
    __hip_bfloat16* W1t  = (__hip_bfloat16*)p;  p += (size_t)E_EXP * D_HID * F_FFN * 2; // 67 MB
    __hip_bfloat16* W2t  = (__hip_bfloat16*)p;  p += (size_t)E_EXP * D_HID * F_FFN * 2; // 67 MB
    __hip_bfloat16* hbuf = (__hip_bfloat16*)p;  p += (size_t)E_EXP * C_CAP * F_FFN * 2; // 134 MB
    // yo aliases W1t (dead after gemm1; gemm2 writes yo, combine reads it).
    float* yo = (float*)W1t;   // E*C*D*4 = 67 MB, exactly W1t's size

    hipMemsetAsync(cnt, 0, (size_t)T_TOK * 4, stream);

    // gating fuses x->bf16 convert and writes the (constant) aux loss
    gating_kernel<<<T_TOK / 4, 256, 0, stream>>>(
        x, Wg, gatesT, x_bf, out + (size_t)T_TOK * D_HID);
    topk_kernel<<<E_EXP, 1024, 0, stream>>>(gatesT, topidx, topval, cnt, inv);

    // both weight transposes in one launch
    {
        dim3 g(F_FFN / 64, D_HID / 64, 2 * E_EXP);
        transpose_bf16_kernel<<<g, 256, 0, stream>>>(W1, W1t, W2, W2t);
    }

    // Batched expert FFN
    gemm1_kernel<<<4096, 256, 0, stream>>>(x_bf, W1t, b1, topidx, hbuf);
    gemm2_kernel<<<256, 512, 0, stream>>>(hbuf, W2t, b2, topval, yo);
    combine_kernel<<<T_TOK, 256, 0, stream>>>(yo, cnt, inv, out);
}

// Round 6
// 665.085 us; speedup vs baseline: 1.0323x; 1.0323x over previous
//
#include <hip/hip_runtime.h>
#include <hip/hip_bf16.h>

// Problem constants
#define T_TOK 8192
#define E_EXP 8
#define D_HID 1024
#define F_FFN 4096
#define C_CAP 2048   // T * 2.0 / E

typedef __attribute__((ext_vector_type(8))) short bf16x8;  // 8 bf16 (4 VGPRs)
typedef __attribute__((ext_vector_type(4))) float f32x4;   // 4 fp32 acc

// Async global->LDS, 16 B per lane. LDS dest is wave-uniform base + lane*16;
// source address may be per-lane (gather OK).
__device__ __forceinline__ void load_lds16(const void* g, void* l) {
    __builtin_amdgcn_global_load_lds(
        (const __attribute__((address_space(1))) unsigned int*)g,
        (__attribute__((address_space(3))) unsigned int*)l, 16, 0, 0);
}

// gelu(v) = v * sigmoid(1.595769 v + 0.0713548 v^3); __expf -> v_exp_f32.
__device__ __forceinline__ float gelu_fast(float v) {
    float z = v * (1.5957691216057308f + 0.07135481627f * v * v);
    return v / (1.0f + __expf(-z));
}

// ---------------------------------------------------------------------------
// Kernel 1: router gating (fp32 exact) + fused x->bf16 convert + aux const.
// aux = E*(C/T)*sum_e mean_t gates = E*(C/T) exactly (softmax rows sum to 1).
// ---------------------------------------------------------------------------
__global__ __launch_bounds__(256) void gating_kernel(
    const float* __restrict__ x, const float* __restrict__ Wg,
    float* __restrict__ gatesT, __hip_bfloat16* __restrict__ xbf,
    float* __restrict__ aux_out)
{
    const int token = blockIdx.x * 4 + (threadIdx.x >> 6);
    const int lane  = threadIdx.x & 63;
    if (token == 0 && lane == 0)
        aux_out[0] = (float)E_EXP * (float)C_CAP / (float)T_TOK;   // == 2.0f
    const float* xr = x + (size_t)token * D_HID;

    float acc[E_EXP];
#pragma unroll
    for (int e = 0; e < E_EXP; ++e) acc[e] = 0.0f;

#pragma unroll
    for (int it = 0; it < 4; ++it) {
        const int c4 = it * 64 + lane;               // float4 index in row
        float4 v = ((const float4*)xr)[c4];
        float vv[4] = {v.x, v.y, v.z, v.w};
        union { __hip_bfloat16 h[4]; short4 s; } u;
#pragma unroll
        for (int j = 0; j < 4; ++j) u.h[j] = __float2bfloat16(vv[j]);
        ((short4*)(xbf + (size_t)token * D_HID))[c4] = u.s;
        const float* wr0 = Wg + (size_t)c4 * 4 * E_EXP;
#pragma unroll
        for (int j = 0; j < 4; ++j)
#pragma unroll
            for (int e = 0; e < E_EXP; ++e) acc[e] += vv[j] * wr0[j * E_EXP + e];
    }
#pragma unroll
    for (int e = 0; e < E_EXP; ++e) {
        for (int off = 32; off; off >>= 1) acc[e] += __shfl_down(acc[e], off);
    }
    if (lane == 0) {
        float m = acc[0];
#pragma unroll
        for (int e = 1; e < E_EXP; ++e) m = fmaxf(m, acc[e]);
        float ex[E_EXP];
        float s = 0.0f;
#pragma unroll
        for (int e = 0; e < E_EXP; ++e) { ex[e] = expf(acc[e] - m); s += ex[e]; }
        float inv = 1.0f / s;
#pragma unroll
        for (int e = 0; e < E_EXP; ++e) gatesT[(size_t)e * T_TOK + token] = ex[e] * inv;
    }
}

// ---------------------------------------------------------------------------
// Kernel 3: exact per-expert top-C via register radix-select, NO sort.
// Selected SET is bit-identical to jax top_k (keys embed the tie-break);
// output order within an expert is irrelevant downstream.
// ---------------------------------------------------------------------------
__global__ __launch_bounds__(1024) void topk_kernel(
    const float* __restrict__ gatesT, int* __restrict__ topidx,
    float* __restrict__ topval, int* __restrict__ cnt, int* __restrict__ inv)
{
    __shared__ unsigned int hist[256];
    __shared__ unsigned int bc_v, bc_r;
    __shared__ unsigned int selcnt;

    const int e    = blockIdx.x;
    const int tid  = threadIdx.x;
    const int lane = tid & 63;
    const float* row = gatesT + (size_t)e * T_TOK;

    unsigned long long kreg[8];
#pragma unroll
    for (int p = 0; p < 8; ++p) {
        int i = tid + p * 1024;
        unsigned int b = __float_as_uint(row[i]);
        b = (b & 0x80000000u) ? ~b : (b | 0x80000000u);
        kreg[p] = ((unsigned long long)b << 32) | (unsigned int)(T_TOK - 1 - i);
    }
    if (tid == 0) selcnt = 0;

    unsigned long long prefix = 0ull, mask = 0ull;
    unsigned int rank = C_CAP;
    for (int byte = 7; byte >= 0; --byte) {
        if (tid < 256) hist[tid] = 0;
        __syncthreads();
        const int sh = byte * 8;
#pragma unroll
        for (int p = 0; p < 8; ++p) {
            unsigned long long k = kreg[p];
            if ((k & mask) == prefix)
                atomicAdd(&hist[(unsigned int)((k >> sh) & 255ull)], 1u);
        }
        __syncthreads();
        if (tid < 64) {
            unsigned int v0 = hist[tid * 4], v1 = hist[tid * 4 + 1];
            unsigned int v2 = hist[tid * 4 + 2], v3 = hist[tid * 4 + 3];
            unsigned int s3 = v3, s2 = v2 + s3, s1 = v1 + s2, s0 = v0 + s1;
            unsigned int t = s0;
#pragma unroll
            for (int off = 1; off < 64; off <<= 1) {
                unsigned int u = __shfl_down(t, off);
                if (lane + off < 64) t += u;
            }
            const unsigned int suf = t - s0;
            unsigned int ge[4] = {s0 + suf, s1 + suf, s2 + suf, s3 + suf};
            unsigned int gt[4] = {s1 + suf, s2 + suf, s3 + suf, suf};
#pragma unroll
            for (int j = 0; j < 4; ++j)
                if (ge[j] >= rank && gt[j] < rank) {
                    bc_v = (unsigned int)(tid * 4 + j); bc_r = rank - gt[j];
                }
        }
        __syncthreads();
        prefix |= ((unsigned long long)bc_v) << sh;
        mask   |= (0xFFull << sh);
        rank = bc_r;
        __syncthreads();
    }
    const unsigned long long thr = prefix;

#pragma unroll
    for (int p = 0; p < 8; ++p) {
        unsigned long long k = kreg[p];
        if (k >= thr) {
            int c = (int)atomicAdd(&selcnt, 1u);
            int idx = T_TOK - 1 - (int)(k & 0xFFFFFFFFull);
            unsigned int b = (unsigned int)(k >> 32);
            b = (b & 0x80000000u) ? (b & 0x7FFFFFFFu) : ~b;
            topidx[e * C_CAP + c] = idx;
            topval[e * C_CAP + c] = __uint_as_float(b);
            int slot = atomicAdd(&cnt[idx], 1);   // <=8 entries per token
            inv[idx * E_EXP + slot] = e * C_CAP + c;
        }
    }
}

// ---------------------------------------------------------------------------
// Kernel 5: both weight transposes in ONE launch.
// z<8:  W1 [D,F] -> W1t [F,D], expert z.  z>=8: W2 [F,D] -> W2t [D,F].
// ---------------------------------------------------------------------------
__global__ __launch_bounds__(256) void transpose_bf16_kernel(
    const float* __restrict__ W1, __hip_bfloat16* __restrict__ W1t,
    const float* __restrict__ W2, __hip_bfloat16* __restrict__ W2t)
{
    __shared__ float tile[64][65];
    const int z = blockIdx.z;
    const float* in;
    __hip_bfloat16* out;
    int R, Cn, c0, r0;
    if (z < 8) {
        R = D_HID; Cn = F_FFN;
        in = W1 + (size_t)z * R * Cn; out = W1t + (size_t)z * R * Cn;
        c0 = blockIdx.x * 64; r0 = blockIdx.y * 64;
    } else {
        R = F_FFN; Cn = D_HID;
        in = W2 + (size_t)(z - 8) * R * Cn; out = W2t + (size_t)(z - 8) * R * Cn;
        c0 = blockIdx.y * 64; r0 = blockIdx.x * 64;
    }
    const int tid = threadIdx.x;

    const int lr = tid >> 4, lc4 = (tid & 15) * 4;
#pragma unroll
    for (int it = 0; it < 4; ++it) {
        int r = lr + it * 16;
        float4 v = *(const float4*)(in + (size_t)(r0 + r) * Cn + c0 + lc4);
        tile[r][lc4 + 0] = v.x; tile[r][lc4 + 1] = v.y;
        tile[r][lc4 + 2] = v.z; tile[r][lc4 + 3] = v.w;
    }
    __syncthreads();

    const int ocb = tid >> 3, j0 = (tid & 7) * 8;
#pragma unroll
    for (int it = 0; it < 2; ++it) {
        int oc = ocb + it * 32;
        union { __hip_bfloat16 h[8]; uint4 v; } u;
#pragma unroll
        for (int j = 0; j < 8; ++j) u.h[j] = __float2bfloat16(tile[j0 + j][oc]);
        *(uint4*)(out + (size_t)(c0 + oc) * R + r0 + j0) = u.v;
    }
}

// ===========================================================================
// 256x256 8-phase GEMM (R2 structure, best measured) with ONE change this
// round: NO sched_barrier(0) pins. Raw s_barrier + lgkmcnt(0) only, exactly
// the verified m201 phase pattern. The compiler is free to emit its own
// fine-grained lgkmcnt(N) between ds_read and MFMA and to overlap phases
// (m141 lesson: sched_barrier(0) order-pinning serializes LDS and MFMA
// pipes). Counted vmcnt stays (compiler can't derive it for gload_lds).
// Correctness: ds_reads are compiler-visible pointer loads, so the compiler
// inserts dependency waits before MFMA uses regardless of our asm waits.
// ===========================================================================

#define BARS __builtin_amdgcn_s_barrier()
#define WLG  asm volatile("s_waitcnt lgkmcnt(0)" ::: "memory")
#define VMC4 asm volatile("s_waitcnt vmcnt(4)" ::: "memory")
#define VMC0 asm volatile("s_waitcnt vmcnt(0)" ::: "memory")

#define G_STAGE_A(hh, s) do { int b_ = (((s) & 1) << 15) + ((hh) << 14) + (w << 10); \
    load_lds16(Abase + (size_t)(aog[hh][0] + (s) * 128), smem + b_); \
    load_lds16(Abase + (size_t)(aog[hh][1] + (s) * 128), smem + b_ + 8192); } while (0)
#define G_STAGE_B(hh, s) do { int b_ = 65536 + (((s) & 1) << 15) + ((hh) << 14) + (w << 10); \
    load_lds16(Bbase + (size_t)(bog[hh][0] + (s) * 128), smem + b_); \
    load_lds16(Bbase + (size_t)(bog[hh][1] + (s) * 128), smem + b_ + 8192); } while (0)

#define READ_A(mh) do { _Pragma("unroll") for (int mi = 0; mi < 4; ++mi) { \
    aF[mi][0] = *(const bf16x8*)(Ab + (arow + (mh) * 8192 + mi * 2048 + kc0)); \
    aF[mi][1] = *(const bf16x8*)(Ab + (arow + (mh) * 8192 + mi * 2048 + kc1)); } } while (0)
#define READ_B(nh, dst) do { _Pragma("unroll") for (int ni = 0; ni < 2; ++ni) { \
    dst[ni][0] = *(const bf16x8*)(Bb + (brow + (nh) * 4096 + ni * 2048 + kc0)); \
    dst[ni][1] = *(const bf16x8*)(Bb + (brow + (nh) * 4096 + ni * 2048 + kc1)); } } while (0)

#define QUAD(mh, nh, BF) do { \
    __builtin_amdgcn_s_setprio(1); \
    _Pragma("unroll") for (int mi = 0; mi < 4; ++mi) \
    _Pragma("unroll") for (int ni = 0; ni < 2; ++ni) { \
        acc[(mh)*4+mi][(nh)*2+ni] = __builtin_amdgcn_mfma_f32_16x16x32_bf16( \
            aF[mi][0], BF[ni][0], acc[(mh)*4+mi][(nh)*2+ni], 0, 0, 0); \
        acc[(mh)*4+mi][(nh)*2+ni] = __builtin_amdgcn_mfma_f32_16x16x32_bf16( \
            aF[mi][1], BF[ni][1], acc[(mh)*4+mi][(nh)*2+ni], 0, 0, 0); } \
    __builtin_amdgcn_s_setprio(0); } while (0)

#define GEMM_PROLOGUE() do { \
    G_STAGE_A(0, 0); G_STAGE_A(1, 0); G_STAGE_B(0, 0); G_STAGE_B(1, 0); \
    G_STAGE_B(0, 1); G_STAGE_B(1, 1); \
    VMC4; BARS; } while (0)

#define GEMM_TILE(t, NT) do { \
    const char* Ab = smem + (((t) & 1) << 15); \
    const char* Bb = smem + 65536 + (((t) & 1) << 15); \
    /* phase 0 */ \
    READ_A(0); READ_B(0, bF0); \
    if ((t) + 1 < (NT)) G_STAGE_A(0, (t) + 1); \
    BARS; WLG; QUAD(0, 0, bF0); BARS; \
    /* phase 1 */ \
    READ_B(1, bF1); \
    if ((t) + 1 < (NT)) G_STAGE_A(1, (t) + 1); \
    BARS; WLG; QUAD(0, 1, bF1); BARS; \
    /* phase 2 */ \
    READ_A(1); \
    if ((t) + 2 < (NT)) G_STAGE_B(0, (t) + 2); \
    BARS; WLG; QUAD(1, 1, bF1); BARS; \
    /* phase 3 */ \
    if ((t) + 2 < (NT)) G_STAGE_B(1, (t) + 2); \
    BARS; WLG; QUAD(1, 0, bF0); \
    if ((t) + 2 < (NT)) { VMC4; } else { VMC0; } \
    BARS; } while (0)

// ---------------------------------------------------------------------------
// Kernel 6: GEMM1 (all experts): h[e] = gelu(gather(x)[C,D] @ W1t[e]^T + b1[e])
// M=C=2048, N=F=4096, K=D=1024. Grid 1024 x 512 thr.
// m-fastest mapping (best FETCH, R2): 32 blocks/XCD share a 2 MB B-slice.
// ---------------------------------------------------------------------------
__global__ __launch_bounds__(512, 2) void gemm1_kernel(
    const __hip_bfloat16* __restrict__ xb,   // [T][D]
    const __hip_bfloat16* __restrict__ W1t,  // [E][F][D]
    const float* __restrict__ b1,            // [E][F]
    const int* __restrict__ topidx,          // [E][C]
    __hip_bfloat16* __restrict__ hbuf)       // [E][C][F]
{
    __shared__ __align__(16) char smem[131072];   // [A0|A1|B0|B1] x 32 KiB
    const int tid = threadIdx.x;
    const int w = tid >> 6, lane = tid & 63;
    const int wr = w >> 2, wc = w & 3;
    const int fr = lane & 15, qlane = lane >> 4;

    // XCD-bijective swizzle (1024 % 8 == 0), m-fastest within expert
    const int bid = blockIdx.x;
    const int wg  = (bid & 7) * 128 + (bid >> 3);
    const int m0  = (wg & 7) * 256;
    const int n0  = ((wg >> 3) & 15) * 256;
    const int e   = wg >> 7;

    const char* Abase = (const char*)xb;
    const char* Bbase = (const char*)(W1t + (size_t)e * F_FFN * D_HID);

    // staging source byte offsets (inverse-swizzled column chunk)
    const int cc = (tid & 7) ^ ((tid >> 3) & 7);
    int aog[2][2], bog[2][2];
#pragma unroll
    for (int hh = 0; hh < 2; ++hh)
#pragma unroll
        for (int j = 0; j < 2; ++j) {
            int r   = m0 + hh * 128 + j * 64 + (tid >> 3);
            int tok = topidx[e * C_CAP + r];
            aog[hh][j] = (tok * D_HID + cc * 8) * 2;
            int n = n0 + hh * 128 + j * 64 + (tid >> 3);
            bog[hh][j] = (n * D_HID + cc * 8) * 2;
        }

    const int arow = (wr * 128 + fr) * 128;
    const int brow = (wc * 64 + fr) * 128;
    const int kc0  = ((qlane)     ^ (lane & 7)) * 16;
    const int kc1  = ((4 + qlane) ^ (lane & 7)) * 16;

    bf16x8 aF[4][2], bF0[2][2], bF1[2][2];
    f32x4 acc[8][4];
#pragma unroll
    for (int mi = 0; mi < 8; ++mi)
#pragma unroll
        for (int ni = 0; ni < 4; ++ni) acc[mi][ni] = (f32x4){0.f, 0.f, 0.f, 0.f};

    GEMM_PROLOGUE();
    for (int t = 0; t < 16; ++t) GEMM_TILE(t, 16);   // NT = 1024/64

    // Epilogue: bias + gelu -> bf16 via full-LDS transpose (128 KiB).
    // Row-XOR swizzled 2-B writes, then b128 reads + 16-B coalesced stores.
    const int q4 = qlane * 4;
    float b1v[4];
#pragma unroll
    for (int ni = 0; ni < 4; ++ni)
        b1v[ni] = b1[e * F_FFN + n0 + wc * 64 + ni * 16 + fr];
    // last GEMM_TILE ended with VMC0 + barrier: LDS free to reuse
#pragma unroll
    for (int mi = 0; mi < 8; ++mi)
#pragma unroll
        for (int r = 0; r < 4; ++r) {
            const int row = wr * 128 + mi * 16 + q4 + r;
            char* rb = smem + row * 512;
            const int sw = (row & 7) << 4;
#pragma unroll
            for (int ni = 0; ni < 4; ++ni) {
                const int col2 = (wc * 64 + ni * 16 + fr) * 2;
                *(__hip_bfloat16*)(rb + (col2 ^ sw)) =
                    __float2bfloat16(gelu_fast(acc[mi][ni][r] + b1v[ni]));
            }
        }
    __syncthreads();
#pragma unroll
    for (int it = 0; it < 16; ++it) {
        const int row = it * 16 + w * 2 + (lane >> 5);
        const int cb  = (lane & 31) * 16;
        uint4 v = *(const uint4*)(smem + row * 512 + (cb ^ ((row & 7) << 4)));
        char* gp = (char*)(hbuf + ((size_t)e * C_CAP + m0 + row) * F_FFN + n0) + cb;
        *(uint4*)gp = v;
    }
}

// ---------------------------------------------------------------------------
// Kernel 7: GEMM2 (all experts): yo[e][c] = (h[e] @ W2t[e]^T + b2[e]) * gate
// M=C=2048, N=D=1024, K=F=4096. Grid 256 x 512 thr (1/CU), NT=64.
// ---------------------------------------------------------------------------
__global__ __launch_bounds__(512, 2) void gemm2_kernel(
    const __hip_bfloat16* __restrict__ hbuf, // [E][C][F]
    const __hip_bfloat16* __restrict__ W2t,  // [E][D][F]
    const float* __restrict__ b2,            // [E][D]
    const float* __restrict__ topval,        // [E][C]
    float* __restrict__ yo)                  // [E][C][D]
{
    __shared__ __align__(16) char smem[131072];
    const int tid = threadIdx.x;
    const int w = tid >> 6, lane = tid & 63;
    const int wr = w >> 2, wc = w & 3;
    const int fr = lane & 15, qlane = lane >> 4;

    const int bid = blockIdx.x;
    const int wg  = (bid & 7) * 32 + (bid >> 3);   // 256 % 8 == 0
    const int n0  = (wg & 3) * 256;
    const int m0  = ((wg >> 2) & 7) * 256;
    const int e   = wg >> 5;                        // one expert per XCD

    const char* Abase = (const char*)(hbuf + (size_t)e * C_CAP * F_FFN);
    const char* Bbase = (const char*)(W2t + (size_t)e * D_HID * F_FFN);

    const int cc = (tid & 7) ^ ((tid >> 3) & 7);
    int aog[2][2], bog[2][2];
#pragma unroll
    for (int hh = 0; hh < 2; ++hh)
#pragma unroll
        for (int j = 0; j < 2; ++j) {
            int r = m0 + hh * 128 + j * 64 + (tid >> 3);
            aog[hh][j] = (r * F_FFN + cc * 8) * 2;
            int n = n0 + hh * 128 + j * 64 + (tid >> 3);
            bog[hh][j] = (n * F_FFN + cc * 8) * 2;
        }

    const int arow = (wr * 128 + fr) * 128;
    const int brow = (wc * 64 + fr) * 128;
    const int kc0  = ((qlane)     ^ (lane & 7)) * 16;
    const int kc1  = ((4 + qlane) ^ (lane & 7)) * 16;

    bf16x8 aF[4][2], bF0[2][2], bF1[2][2];
    f32x4 acc[8][4];
#pragma unroll
    for (int mi = 0; mi < 8; ++mi)
#pragma unroll
        for (int ni = 0; ni < 4; ++ni) acc[mi][ni] = (f32x4){0.f, 0.f, 0.f, 0.f};

    GEMM_PROLOGUE();
    for (int t = 0; t < 64; ++t) GEMM_TILE(t, 64);   // NT = 4096/64

    // Epilogue: bias + gate weight, fp32; 16-lane groups write 64 B runs.
    const int q4 = qlane * 4;
    float b2v[4];
#pragma unroll
    for (int ni = 0; ni < 4; ++ni)
        b2v[ni] = b2[e * D_HID + n0 + wc * 64 + ni * 16 + fr];
#pragma unroll
    for (int mi = 0; mi < 8; ++mi) {
#pragma unroll
        for (int r = 0; r < 4; ++r) {
            const int row = m0 + wr * 128 + mi * 16 + q4 + r;
            const float g = topval[e * C_CAP + row];
            float* orow = yo + ((size_t)e * C_CAP + row) * D_HID + n0 + wc * 64;
#pragma unroll
            for (int ni = 0; ni < 4; ++ni)
                orow[ni * 16 + fr] = (acc[mi][ni][r] + b2v[ni]) * g;
        }
    }
}

// ---------------------------------------------------------------------------
// Kernel 8: combine — out[t] = sum over inv[t] entries of yo rows.
// ---------------------------------------------------------------------------
__global__ __launch_bounds__(256) void combine_kernel(
    const float* __restrict__ yo, const int* __restrict__ cnt,
    const int* __restrict__ inv, float* __restrict__ out)
{
    const int t = blockIdx.x;
    const int n = cnt[t];
    const int c4 = threadIdx.x * 4;
    float4 a = {0.f, 0.f, 0.f, 0.f};
    for (int k = 0; k < n; ++k) {
        int ec = inv[t * E_EXP + k];
        float4 v = *(const float4*)(yo + (size_t)ec * D_HID + c4);
        a.x += v.x; a.y += v.y; a.z += v.z; a.w += v.w;
    }
    *(float4*)(out + (size_t)t * D_HID + c4) = a;
}

// ---------------------------------------------------------------------------
extern "C" void kernel_launch(void* const* d_in, const int* in_sizes, int n_in,
                              void* d_out, int out_size, void* d_ws, size_t ws_size,
                              hipStream_t stream) {
    const float* x  = (const float*)d_in[0];   // [T, D]
    const float* Wg = (const float*)d_in[1];   // [D, E]
    const float* W1 = (const float*)d_in[2];   // [E, D, F]
    const float* b1 = (const float*)d_in[3];   // [E, F]
    const float* W2 = (const float*)d_in[4];   // [E, F, D]
    const float* b2 = (const float*)d_in[5];   // [E, D]
    float* out = (float*)d_out;                // [T*D] out ++ [1] aux

    // Workspace layout
    char* p = (char*)d_ws;
    float* gatesT = (float*)p;            p += (size_t)E_EXP * T_TOK * 4;      // 256 KB
    int*   topidx = (int*)p;              p += (size_t)E_EXP * C_CAP * 4;      // 64 KB
    float* topval = (float*)p;            p += (size_t)E_EXP * C_CAP * 4;      // 64 KB
    int*   cnt    = (int*)p;              p += (size_t)T_TOK * 4;              // 32 KB
    int*   inv    = (int*)p;              p += (size_t)T_TOK * E_EXP * 4;      // 256 KB
    __hip_bfloat16* x_bf = (__hip_bfloat16*)p;  p += (size_t)T_TOK * D_HID * 2;         // 16.8 MB
    __hip_bfloat16* W1t  = (__hip_bfloat16*)p;  p += (size_t)E_EXP * D_HID * F_FFN * 2; // 67 MB
    __hip_bfloat16* W2t  = (__hip_bfloat16*)p;  p += (size_t)E_EXP * D_HID * F_FFN * 2; // 67 MB
    __hip_bfloat16* hbuf = (__hip_bfloat16*)p;  p += (size_t)E_EXP * C_CAP * F_FFN * 2; // 134 MB
    // yo aliases W1t (dead after gemm1; gemm2 writes yo, combine reads it).
    float* yo = (float*)W1t;   // E*C*D*4 = 67 MB, exactly W1t's size

    hipMemsetAsync(cnt, 0, (size_t)T_TOK * 4, stream);

    // gating fuses x->bf16 convert and writes the (constant) aux loss
    gating_kernel<<<T_TOK / 4, 256, 0, stream>>>(
        x, Wg, gatesT, x_bf, out + (size_t)T_TOK * D_HID);
    topk_kernel<<<E_EXP, 1024, 0, stream>>>(gatesT, topidx, topval, cnt, inv);

    // both weight transposes in one launch
    {
        dim3 g(F_FFN / 64, D_HID / 64, 2 * E_EXP);
        transpose_bf16_kernel<<<g, 256, 0, stream>>>(W1, W1t, W2, W2t);
    }

    // Batched expert FFN: 256x256 8-phase MFMA GEMMs (no sched pins)
    gemm1_kernel<<<1024, 512, 0, stream>>>(x_bf, W1t, b1, topidx, hbuf);
    gemm2_kernel<<<256, 512, 0, stream>>>(hbuf, W2t, b2, topval, yo);
    combine_kernel<<<T_TOK, 256, 0, stream>>>(yo, cnt, inv, out);
}